// Round 7
// baseline (3399.330 us; speedup 1.0000x reference)
//
#include <hip/hip_runtime.h>
#include <hip/hip_bf16.h>

#define B_   32
#define T_   512
#define H_   1024
#define L_   256
#define V_   13
#define G4H  4096
#define KHL  1280   // H + L

typedef float f32x4 __attribute__((ext_vector_type(4)));
typedef short s16x8 __attribute__((ext_vector_type(8)));
typedef unsigned short u16;
typedef unsigned int   u32;
typedef unsigned long long u64;

// ---------------- ws layout (bytes) ----------------
// Ax  : u16 [1026][16384]    @ 0           (33,619,968)  h chain, MFMA frag layout
//        slab (s,mt) at (s*2+mt)*32768 B; producer p's data = 1KB chunk p
// Bf  : u16 [4,194,304]      @ 33,619,968  (8,388,608)   W_hh A-fragments
// Bf2 : u16 [1,310,720]      @ 42,008,576  (2,621,440)   Wnl  B-fragments
// Az  : u16 [2][4096]        @ 44,630,016  (16,384)      latent frag layout
// bar : int [2][512]         @ 44,646,400  (4,096)
//        group mt: ticket counter at bar[mt*512] (own 64B line);
//        per-WAVE flags at bar[mt*512 + 32 + f], f = p*8+w in [0,256)
// mid : u16 [16384][1024]    @ 44,650,496  (33,554,432)
//   Gx (f32[57344]) and tok (u16[16384]) overlay mid (read only in k_recur).
#define OFF_BF   33619968u
#define OFF_BF2  42008576u
#define OFF_AZ   44630016u
#define OFF_BAR  44646400u
#define OFF_MID  44650496u
#define OFF_GX   OFF_MID                  // 229,376 B  = [jg][14][4] f32
#define OFF_TOK  (OFF_MID + 229376u)      //  32,768 B

__device__ __forceinline__ u16 f2bf(float f) {
    union { float f; u32 u; } v; v.f = f;
    u32 u = v.u;
    u32 r = (u + 0x7fffu + ((u >> 16) & 1u)) >> 16;   // RNE
    return (u16)r;
}
__device__ __forceinline__ float bf2f(u16 h) {
    union { u32 u; float f; } v; v.u = ((u32)h) << 16;
    return v.f;
}
__device__ __forceinline__ float sigm_(float x) {
    x = fminf(fmaxf(x, -30.f), 30.f);
    return 1.f / (1.f + __expf(-x));
}
__device__ __forceinline__ float tanh_(float x) {
    x = fminf(fmaxf(x, -15.f), 15.f);
    float e = __expf(2.f * x);
    return (e - 1.f) / (e + 1.f);
}

// fragment position of (lane-dim index bl, k) within a 16384-u16 slab
__device__ __forceinline__ u32 afrag_pos(int bl, int k) {
    return (u32)((k >> 5) * 512 + ((bl | (((k >> 3) & 3) << 4)) << 3) + (k & 7));
}

// ---------------------------------------------------------------------------
__global__ __launch_bounds__(256) void k_init_misc(
        const float* __restrict__ latent, const float* __restrict__ Wz,
        const float* __restrict__ bz,
        u16* __restrict__ Ax, u16* __restrict__ Az, int* __restrict__ bar) {
    int gid = blockIdx.x * 256 + threadIdx.x;          // [0, 32768)
    int b = gid >> 10, j = gid & 1023;
    const float* lrow = latent + b * L_;
    const float* wrow = Wz + j * L_;
    float acc = bz[j];
    #pragma unroll 4
    for (int l = 0; l < L_; ++l) acc += lrow[l] * wrow[l];
    Ax[(b >> 4) * 16384 + afrag_pos(b & 15, j)] = f2bf(fmaxf(acc, 0.f));
    if (gid < B_ * L_) {
        int bb = gid >> 8, l = gid & 255;
        Az[(bb >> 4) * 4096 + afrag_pos(bb & 15, l)] = f2bf(latent[gid]);
    }
    if (gid < 1024) bar[gid] = 0;
}

// Gx[jg][t][gg] (t in [0,14), gg gate): W_ih[gg*H+jg][t] + b_ih + b_hh ; t=13 -> bias only
__global__ __launch_bounds__(256) void k_init_gx(
        const float* __restrict__ W_ih, const float* __restrict__ b_ih,
        const float* __restrict__ b_hh, float* __restrict__ Gx) {
    int row = blockIdx.x * 256 + threadIdx.x;          // [0,4096)
    if (row >= G4H) return;
    int gg = row >> 10, jg = row & 1023;
    float base = b_ih[row] + b_hh[row];
    float* d = Gx + (size_t)jg * 56;
    const float* wr = W_ih + (size_t)row * V_;
    #pragma unroll
    for (int t = 0; t < V_; ++t) d[t * 4 + gg] = base + wr[t];
    d[13 * 4 + gg] = base;
}

// tok[s*32+b] = one-hot index of seq[b,s,:] (13 if all-zero start row)
__global__ __launch_bounds__(256) void k_init_tok(
        const float* __restrict__ seq, u16* __restrict__ tok) {
    int gid = blockIdx.x * 256 + threadIdx.x;          // [0,16384)
    int s = gid >> 5, b = gid & 31;
    const float* r = seq + ((size_t)b * T_ + s) * V_;
    int t = 13;
    #pragma unroll
    for (int v = 0; v < V_; ++v) if (r[v] > 0.5f) t = v;
    tok[gid] = (u16)t;
}

// W_hh -> MFMA A-fragments. Tile col u = jj*4 + gate.
__global__ __launch_bounds__(256) void k_init_wfrag(
        const float* __restrict__ W_hh, u16* __restrict__ Bf) {
    int base = blockIdx.x * 256 + threadIdx.x;         // 2048 blocks
    #pragma unroll
    for (int i = 0; i < 8; ++i) {
        int idx = base + i * 524288;                   // [0, 4194304)
        int jv   = idx & 7;
        int lane = (idx >> 3) & 63;
        int kc   = (idx >> 9) & 31;
        int nt   = idx >> 14;
        int u = lane & 15;
        int row = (u & 3) * H_ + nt * 4 + (u >> 2);
        int k = kc * 32 + (lane >> 4) * 8 + jv;
        Bf[idx] = f2bf(W_hh[row * H_ + k]);
    }
}

__global__ __launch_bounds__(256) void k_init_wfrag2(
        const float* __restrict__ Wnl, u16* __restrict__ Bf2) {
    int idx = blockIdx.x * 256 + threadIdx.x;
    for (; idx < 1310720; idx += 524288) {
        int jv   = idx & 7;
        int lane = (idx >> 3) & 63;
        int q    = idx >> 9;                           // nt2*40 + kc
        int kc   = q % 40;
        int nt2  = q / 40;
        int n = nt2 * 16 + (lane & 15);
        int k = kc * 32 + (lane >> 4) * 8 + jv;
        Bf2[idx] = f2bf(Wnl[n * KHL + k]);
    }
}

// ---------------------------------------------------------------------------
// Persistent LSTM recurrence, XCD-local exchange (R4 skeleton) with PER-WAVE
// flag publish and double-buffered LDS (no second __syncthreads).
// 512 candidate blocks x 512 thr; XCD ticket claim via AGENT-scope fetch_add
// (LLC, globally coherent); first 32 claimants on XCD0/XCD1 become group 0/1,
// rest exit. h stores are PLAIN (write-through -> dirty in the local L2);
// flag polls are AGENT-scope loads (L1-bypass, serviced by local L2).
// CHANGE vs R4: the second barrier (block-wide vmcnt drain + tid0 publish)
// made the SLOWEST wave gate the whole block's publication. Now each wave
// drains only its own h-stores (wave-local s_waitcnt vmcnt(0), acks at local
// L2) and lane 0 publishes its own flag (256 flags/group, f = p*8 + w).
// WAR safety without barrier #2: LDS slab is double-buffered; a wave stages
// s+1 into buf[(s+1)&1] while laggards read buf[s&1]. No wave can be 2 steps
// ahead: to exit the (per-step) staging barrier of s+1, every block-mate must
// have finished its s-step MFMA reads, so buf[s&1] is only rewritten (at
// stage of s+2) after all reads of step s completed.
__global__ __launch_bounds__(512, 1) void k_recur(
        const u16* __restrict__ tokbuf, const float* __restrict__ Gx,
        const u16* __restrict__ Bf, u16* __restrict__ Ax,
        int* __restrict__ bar) {
    __shared__ uint4 AhV[2][2048];        // 2 x 32 KB h slab (frag layout)
    __shared__ int sh_info;
    int tid = threadIdx.x;

    // ---- claim an XCD-local worker slot (proven in R4) ----
    if (tid == 0) {
        u32 xcc = 0;
        asm volatile("s_getreg_b32 %0, hwreg(HW_REG_XCC_ID)" : "=s"(xcc));
        xcc &= 7u;
        int t = -1;
        if (xcc < 2u) {
            int tk = __hip_atomic_fetch_add(bar + (int)xcc * 512, 1,
                         __ATOMIC_RELAXED, __HIP_MEMORY_SCOPE_AGENT);
            if (tk < 32) t = ((int)xcc << 5) | tk;
        }
        sh_info = t;
    }
    __syncthreads();
    int info = sh_info;
    if (info < 0) return;                 // not a worker
    int mt = info >> 5;                   // group == physical XCD (0 or 1)
    int p  = info & 31;                   // producer index [0,32)

    int w = tid >> 6, L = tid & 63;
    int nt = p * 8 + w;                   // [0,256)
    int lm = L & 15, quad = L >> 4;

    // W_hh A-fragments -> registers (128 VGPRs; R6 showed 256 spills)
    s16x8 afr[32];
    {
        const u16* bfp = Bf + (size_t)nt * 16384 + L * 8;
        #pragma unroll
        for (int kc = 0; kc < 32; ++kc)
            afr[kc] = *reinterpret_cast<const s16x8*>(bfp + kc * 512);
    }
    int jg = nt * 4 + quad;               // this lane's output column
    int b = mt * 16 + lm;                 // this lane's batch
    const float* gxp = Gx + (size_t)jg * 56;
    u32 posu16 = (u32)((nt >> 3) * 512 + ((lm | (((nt >> 1) & 3) << 4)) << 3)
                       + (nt & 1) * 4 + quad);
    int* flags = bar + mt * 512 + 32;     // 256 per-wave flags, 1 dword each
    // wave w stages chunks {8i+w}; chunk c is block c's output = 8 wave flags.
    // lanes 0..31 poll flag f = 64*(li>>3) + 8*w + (li&7); lanes 32..63 mirror.
    int li = L & 31;
    const int* myflag = flags + (((li >> 3) * 8 + w) * 8 + (li & 7));
    int* myflagout = flags + (p * 8 + w);
    u32* AxD = (u32*)Ax;
    float c = 0.f;

    for (int s = 0; s < T_; ++s) {
        // prefetch x-term (independent of slab)
        int tok = tokbuf[s * 32 + b];
        float4 gx4 = *reinterpret_cast<const float4*>(gxp + tok * 4);

        // wave-local: wait for the 32 producer-waves of this wave's 4 chunks
        for (;;) {
            int v = __hip_atomic_load(myflag, __ATOMIC_RELAXED,
                                      __HIP_MEMORY_SCOPE_AGENT);
            if (__all(v >= s)) break;
            __builtin_amdgcn_s_sleep(1);
        }
        // stage this wave's 4 chunks (i*8+w) with cacheable 16B loads
        // (write-once addresses; flags order visibility; local-L2 hits)
        const uint4* srcq = (const uint4*)((const char*)Ax
                             + ((size_t)s * 2 + mt) * 32768);
        uint4* dstq = &AhV[s & 1][0];
        #pragma unroll
        for (int i = 0; i < 4; ++i)
            dstq[i * 512 + tid] = srcq[i * 512 + tid];
        __syncthreads();                  // whole slab resident in LDS

        // gates tile: A = W frags (regs), B = h frags (LDS); 4 indep chains
        f32x4 a0 = {0.f,0.f,0.f,0.f}, a1 = {0.f,0.f,0.f,0.f};
        f32x4 a2 = {0.f,0.f,0.f,0.f}, a3 = {0.f,0.f,0.f,0.f};
        const u16* hp = (const u16*)dstq + L * 8;
        #pragma unroll
        for (int kc = 0; kc < 32; kc += 4) {
            s16x8 h0 = *reinterpret_cast<const s16x8*>(hp + kc * 512);
            s16x8 h1 = *reinterpret_cast<const s16x8*>(hp + (kc + 1) * 512);
            s16x8 h2 = *reinterpret_cast<const s16x8*>(hp + (kc + 2) * 512);
            s16x8 h3 = *reinterpret_cast<const s16x8*>(hp + (kc + 3) * 512);
            a0 = __builtin_amdgcn_mfma_f32_16x16x32_bf16(afr[kc],     h0, a0, 0, 0, 0);
            a1 = __builtin_amdgcn_mfma_f32_16x16x32_bf16(afr[kc + 1], h1, a1, 0, 0, 0);
            a2 = __builtin_amdgcn_mfma_f32_16x16x32_bf16(afr[kc + 2], h2, a2, 0, 0, 0);
            a3 = __builtin_amdgcn_mfma_f32_16x16x32_bf16(afr[kc + 3], h3, a3, 0, 0, 0);
        }
        // acc[r] = gate r (i,f,g,o) for (b, jg)
        float gi = a0[0] + a1[0] + a2[0] + a3[0] + gx4.x;
        float gf = a0[1] + a1[1] + a2[1] + a3[1] + gx4.y;
        float gg = a0[2] + a1[2] + a2[2] + a3[2] + gx4.z;
        float go = a0[3] + a1[3] + a2[3] + a3[3] + gx4.w;
        float ig = sigm_(gi), fg = sigm_(gf);
        float gt = tanh_(gg), og = sigm_(go);
        c = fg * c + ig * gt;
        float hv = og * tanh_(c);

        // write h(s+1): pack 2 bf16/dword, PLAIN store (dirty in local L2)
        u32 bits = (u32)f2bf(hv);
        u32 other = (u32)(u16)__shfl_xor((int)bits, 16);
        if (!(quad & 1)) {
            u32 word = bits | (other << 16);
            AxD[((size_t)(s + 1) * 2 + mt) * 8192 + (posu16 >> 1)] = word;
        }
        if (s == T_ - 1) break;           // final slab drains at kernel end

        // per-wave publish: drain OWN h-stores (acks at local L2), then
        // lane 0 publishes this wave's flag. No block-wide barrier.
        asm volatile("s_waitcnt vmcnt(0)" ::: "memory");
        if (L == 0)
            __hip_atomic_store(myflagout, s + 1, __ATOMIC_RELAXED,
                               __HIP_MEMORY_SCOPE_AGENT);
    }
}

// ---------------------------------------------------------------------------
// mid = relu(feat @ Wnl^T + bnl) — A/B frags straight from global, no LDS.
__global__ __launch_bounds__(256) void k_gemm1(
        const u16* __restrict__ Ax, const u16* __restrict__ Az,
        const u16* __restrict__ Bf2, const float* __restrict__ bnl,
        u16* __restrict__ mid) {
    int tid = threadIdx.x;
    int nb = blockIdx.x;                  // [0,16)
    int mb = blockIdx.y;                  // [0,128)
    int w = tid >> 6, L = tid & 63;
    int lm = L & 15, quad = L >> 4;
    int mti0 = mb * 8 + w * 2;
    const u16* a0p = Ax + ((size_t)mti0 + 2) * 16384 + L * 8;
    const u16* a1p = a0p + 16384;
    const u16* az0 = Az + L * 8;
    const u16* az1 = az0 + 4096;
    const u16* bp = Bf2 + (size_t)(nb * 4) * 40 * 512 + L * 8;

    f32x4 acc[2][4];
    #pragma unroll
    for (int a = 0; a < 2; ++a)
        #pragma unroll
        for (int n = 0; n < 4; ++n) acc[a][n] = (f32x4){0.f, 0.f, 0.f, 0.f};

    #pragma unroll 4
    for (int kc = 0; kc < 32; ++kc) {
        s16x8 a0 = *reinterpret_cast<const s16x8*>(a0p + kc * 512);
        s16x8 a1 = *reinterpret_cast<const s16x8*>(a1p + kc * 512);
        #pragma unroll
        for (int n4 = 0; n4 < 4; ++n4) {
            s16x8 bv = *reinterpret_cast<const s16x8*>(bp + ((size_t)n4 * 40 + kc) * 512);
            acc[0][n4] = __builtin_amdgcn_mfma_f32_16x16x32_bf16(a0, bv, acc[0][n4], 0, 0, 0);
            acc[1][n4] = __builtin_amdgcn_mfma_f32_16x16x32_bf16(a1, bv, acc[1][n4], 0, 0, 0);
        }
    }
    #pragma unroll
    for (int kc2 = 0; kc2 < 8; ++kc2) {
        s16x8 a0 = *reinterpret_cast<const s16x8*>(az0 + kc2 * 512);
        s16x8 a1 = *reinterpret_cast<const s16x8*>(az1 + kc2 * 512);
        #pragma unroll
        for (int n4 = 0; n4 < 4; ++n4) {
            s16x8 bv = *reinterpret_cast<const s16x8*>(bp + ((size_t)n4 * 40 + 32 + kc2) * 512);
            acc[0][n4] = __builtin_amdgcn_mfma_f32_16x16x32_bf16(a0, bv, acc[0][n4], 0, 0, 0);
            acc[1][n4] = __builtin_amdgcn_mfma_f32_16x16x32_bf16(a1, bv, acc[1][n4], 0, 0, 0);
        }
    }
    #pragma unroll
    for (int mt2 = 0; mt2 < 2; ++mt2)
        #pragma unroll
        for (int n4 = 0; n4 < 4; ++n4)
            #pragma unroll
            for (int r = 0; r < 4; ++r) {
                int m = mb * 128 + w * 32 + mt2 * 16 + quad * 4 + r;
                int n = (nb * 4 + n4) * 16 + lm;
                float v = acc[mt2][n4][r] + bnl[n];
                mid[(size_t)m * H_ + n] = f2bf(fmaxf(v, 0.f));
            }
}

// ---------------------------------------------------------------------------
__global__ __launch_bounds__(256) void k_loss(
        const u16* __restrict__ mid, const float* __restrict__ Wout,
        const float* __restrict__ bout, const int* __restrict__ labels,
        const int* __restrict__ lengths, float* __restrict__ out) {
    int mrow = blockIdx.x;                // m = t*32 + b
    int b = mrow & 31, t = mrow >> 5;
    if (t >= lengths[b]) return;
    int tid = threadIdx.x;
    float p[V_];
    #pragma unroll
    for (int v = 0; v < V_; ++v) p[v] = 0.f;
    uint2 raw = *reinterpret_cast<const uint2*>(mid + (size_t)mrow * H_ + tid * 4);
    const u16* rs = (const u16*)&raw;
    float mv0 = bf2f(rs[0]), mv1 = bf2f(rs[1]), mv2 = bf2f(rs[2]), mv3 = bf2f(rs[3]);
    #pragma unroll
    for (int v = 0; v < V_; ++v) {
        float4 wv = *reinterpret_cast<const float4*>(Wout + v * H_ + tid * 4);
        p[v] = mv0 * wv.x + mv1 * wv.y + mv2 * wv.z + mv3 * wv.w;
    }
    #pragma unroll
    for (int off = 32; off > 0; off >>= 1)
        #pragma unroll
        for (int v = 0; v < V_; ++v) p[v] += __shfl_down(p[v], off);
    __shared__ float red[4][V_];
    int w = tid >> 6, L = tid & 63;
    if (L == 0)
        #pragma unroll
        for (int v = 0; v < V_; ++v) red[w][v] = p[v];
    __syncthreads();
    if (tid == 0) {
        float lg[V_]; float mx = -1e30f;
        #pragma unroll
        for (int v = 0; v < V_; ++v) {
            lg[v] = red[0][v] + red[1][v] + red[2][v] + red[3][v] + bout[v];
            mx = fmaxf(mx, lg[v]);
        }
        float se = 0.f;
        #pragma unroll
        for (int v = 0; v < V_; ++v) se += __expf(lg[v] - mx);
        float lse = mx + logf(se);
        int lab = labels[b * T_ + t];
        atomicAdd(&out[1 + b], lse - lg[lab]);
    }
}

__global__ void k_final(float* __restrict__ out) {
    float s = 0.f;
    for (int b = 0; b < B_; ++b) s += out[1 + b];
    out[0] = s;
}

// ---------------------------------------------------------------------------
extern "C" void kernel_launch(void* const* d_in, const int* in_sizes, int n_in,
                              void* d_out, int out_size, void* d_ws, size_t ws_size,
                              hipStream_t stream) {
    const float* seq    = (const float*)d_in[0];
    const float* latent = (const float*)d_in[1];
    const int*   labels = (const int*)d_in[2];
    const int*   lengths= (const int*)d_in[3];
    const float* W_ih   = (const float*)d_in[4];
    const float* W_hh   = (const float*)d_in[5];
    const float* b_ih   = (const float*)d_in[6];
    const float* b_hh   = (const float*)d_in[7];
    const float* Wz     = (const float*)d_in[8];
    const float* bz     = (const float*)d_in[9];
    const float* Wnl    = (const float*)d_in[10];
    const float* bnl    = (const float*)d_in[11];
    const float* Wout   = (const float*)d_in[12];
    const float* bout   = (const float*)d_in[13];

    char* ws = (char*)d_ws;
    u16*   Ax   = (u16*)(ws);
    u16*   Bf   = (u16*)(ws + OFF_BF);
    u16*   Bf2  = (u16*)(ws + OFF_BF2);
    u16*   Az   = (u16*)(ws + OFF_AZ);
    int*   bar  = (int*)(ws + OFF_BAR);
    u16*   mid  = (u16*)(ws + OFF_MID);
    float* Gx   = (float*)(ws + OFF_GX);
    u16*   tok  = (u16*)(ws + OFF_TOK);
    float* out  = (float*)d_out;

    hipMemsetAsync(d_out, 0, 33 * sizeof(float), stream);
    k_init_misc<<<128, 256, 0, stream>>>(latent, Wz, bz, Ax, Az, bar);
    k_init_gx<<<16, 256, 0, stream>>>(W_ih, b_ih, b_hh, Gx);
    k_init_tok<<<64, 256, 0, stream>>>(seq, tok);
    k_init_wfrag<<<2048, 256, 0, stream>>>(W_hh, Bf);
    k_init_wfrag2<<<2048, 256, 0, stream>>>(Wnl, Bf2);
    k_recur<<<512, 512, 0, stream>>>(tok, Gx, Bf, Ax, bar);
    k_gemm1<<<dim3(16, 128), 256, 0, stream>>>(Ax, Az, Bf2, bnl, mid);
    k_loss<<<16384, 256, 0, stream>>>(mid, Wout, bout, labels, lengths, out);
    k_final<<<1, 1, 0, stream>>>(out);
}

// Round 8
// 2339.958 us; speedup vs baseline: 1.4527x; 1.4527x over previous
//
#include <hip/hip_runtime.h>
#include <hip/hip_bf16.h>

#define B_   32
#define T_   512
#define H_   1024
#define L_   256
#define V_   13
#define G4H  4096
#define KHL  1280   // H + L

typedef float f32x4 __attribute__((ext_vector_type(4)));
typedef short s16x8 __attribute__((ext_vector_type(8)));
typedef unsigned short u16;
typedef unsigned int   u32;
typedef unsigned long long u64;

// ---------------- ws layout (bytes) ----------------
// Ax  : u16 [1026][16384]    @ 0           (33,619,968)  h chain, MFMA frag layout
//        slab (s,mt) at (s*2+mt)*32768 B; producer p's data = 1KB chunk p
// Bf  : u16 [4,194,304]      @ 33,619,968  (8,388,608)   W_hh A-fragments
// Bf2 : u16 [1,310,720]      @ 42,008,576  (2,621,440)   Wnl  B-fragments
// Az  : u16 [2][4096]        @ 44,630,016  (16,384)      latent frag layout
// bar : int [2][512]         @ 44,646,400  (4,096)
//        group mt: ticket counter at bar[mt*512] (own 64B line);
//        block p: flag at bar[mt*512+16+p*8], drain counter at +p*8+4
// mid : u16 [16384][1024]    @ 44,650,496  (33,554,432)
//   Gx (f32[57344]) and tok (u16[16384]) overlay mid (read only in k_recur).
#define OFF_BF   33619968u
#define OFF_BF2  42008576u
#define OFF_AZ   44630016u
#define OFF_BAR  44646400u
#define OFF_MID  44650496u
#define OFF_GX   OFF_MID                  // 229,376 B  = [jg][14][4] f32
#define OFF_TOK  (OFF_MID + 229376u)      //  32,768 B

__device__ __forceinline__ u16 f2bf(float f) {
    union { float f; u32 u; } v; v.f = f;
    u32 u = v.u;
    u32 r = (u + 0x7fffu + ((u >> 16) & 1u)) >> 16;   // RNE
    return (u16)r;
}
__device__ __forceinline__ float bf2f(u16 h) {
    union { u32 u; float f; } v; v.u = ((u32)h) << 16;
    return v.f;
}
__device__ __forceinline__ float sigm_(float x) {
    x = fminf(fmaxf(x, -30.f), 30.f);
    return 1.f / (1.f + __expf(-x));
}
__device__ __forceinline__ float tanh_(float x) {
    x = fminf(fmaxf(x, -15.f), 15.f);
    float e = __expf(2.f * x);
    return (e - 1.f) / (e + 1.f);
}

// fragment position of (lane-dim index bl, k) within a 16384-u16 slab
__device__ __forceinline__ u32 afrag_pos(int bl, int k) {
    return (u32)((k >> 5) * 512 + ((bl | (((k >> 3) & 3) << 4)) << 3) + (k & 7));
}

// ---------------------------------------------------------------------------
__global__ __launch_bounds__(256) void k_init_misc(
        const float* __restrict__ latent, const float* __restrict__ Wz,
        const float* __restrict__ bz,
        u16* __restrict__ Ax, u16* __restrict__ Az, int* __restrict__ bar) {
    int gid = blockIdx.x * 256 + threadIdx.x;          // [0, 32768)
    int b = gid >> 10, j = gid & 1023;
    const float* lrow = latent + b * L_;
    const float* wrow = Wz + j * L_;
    float acc = bz[j];
    #pragma unroll 4
    for (int l = 0; l < L_; ++l) acc += lrow[l] * wrow[l];
    Ax[(b >> 4) * 16384 + afrag_pos(b & 15, j)] = f2bf(fmaxf(acc, 0.f));
    if (gid < B_ * L_) {
        int bb = gid >> 8, l = gid & 255;
        Az[(bb >> 4) * 4096 + afrag_pos(bb & 15, l)] = f2bf(latent[gid]);
    }
    if (gid < 1024) bar[gid] = 0;
}

// Gx[jg][t][gg] (t in [0,14), gg gate): W_ih[gg*H+jg][t] + b_ih + b_hh ; t=13 -> bias only
__global__ __launch_bounds__(256) void k_init_gx(
        const float* __restrict__ W_ih, const float* __restrict__ b_ih,
        const float* __restrict__ b_hh, float* __restrict__ Gx) {
    int row = blockIdx.x * 256 + threadIdx.x;          // [0,4096)
    if (row >= G4H) return;
    int gg = row >> 10, jg = row & 1023;
    float base = b_ih[row] + b_hh[row];
    float* d = Gx + (size_t)jg * 56;
    const float* wr = W_ih + (size_t)row * V_;
    #pragma unroll
    for (int t = 0; t < V_; ++t) d[t * 4 + gg] = base + wr[t];
    d[13 * 4 + gg] = base;
}

// tok[s*32+b] = one-hot index of seq[b,s,:] (13 if all-zero start row)
__global__ __launch_bounds__(256) void k_init_tok(
        const float* __restrict__ seq, u16* __restrict__ tok) {
    int gid = blockIdx.x * 256 + threadIdx.x;          // [0,16384)
    int s = gid >> 5, b = gid & 31;
    const float* r = seq + ((size_t)b * T_ + s) * V_;
    int t = 13;
    #pragma unroll
    for (int v = 0; v < V_; ++v) if (r[v] > 0.5f) t = v;
    tok[gid] = (u16)t;
}

// W_hh -> MFMA A-fragments. Tile col u = jj*4 + gate.
__global__ __launch_bounds__(256) void k_init_wfrag(
        const float* __restrict__ W_hh, u16* __restrict__ Bf) {
    int base = blockIdx.x * 256 + threadIdx.x;         // 2048 blocks
    #pragma unroll
    for (int i = 0; i < 8; ++i) {
        int idx = base + i * 524288;                   // [0, 4194304)
        int jv   = idx & 7;
        int lane = (idx >> 3) & 63;
        int kc   = (idx >> 9) & 31;
        int nt   = idx >> 14;
        int u = lane & 15;
        int row = (u & 3) * H_ + nt * 4 + (u >> 2);
        int k = kc * 32 + (lane >> 4) * 8 + jv;
        Bf[idx] = f2bf(W_hh[row * H_ + k]);
    }
}

__global__ __launch_bounds__(256) void k_init_wfrag2(
        const float* __restrict__ Wnl, u16* __restrict__ Bf2) {
    int idx = blockIdx.x * 256 + threadIdx.x;
    for (; idx < 1310720; idx += 524288) {
        int jv   = idx & 7;
        int lane = (idx >> 3) & 63;
        int q    = idx >> 9;                           // nt2*40 + kc
        int kc   = q % 40;
        int nt2  = q / 40;
        int n = nt2 * 16 + (lane & 15);
        int k = kc * 32 + (lane >> 4) * 8 + jv;
        Bf2[idx] = f2bf(Wnl[n * KHL + k]);
    }
}

// ---------------------------------------------------------------------------
// Persistent LSTM recurrence, XCD-local exchange (R4 skeleton) with:
//  (a) per-chunk pipelined staging: poll chunk flag (all lanes, same addr =
//      one broadcast transaction) then immediately load that chunk;
//  (b) ONE barrier per step: LDS double-buffered. WAR proof: a wave stages
//      s+2 into buf[s&1] only after passing barrier #1 of step s+1, which
//      every wave reaches only after completing its step-s LDS reads.
//  (c) early publish: each wave drains its OWN h-stores (vmcnt(0), acks at
//      local L2) then lane0 bumps a per-block counter (workgroup scope, all
//      8 waves share this CU); the 8th incrementer publishes the SAME single
//      per-block flag as R4 (coarse granularity preserved -- R7 showed
//      fine-grained flags thrash L2). Publish fires at last-wave-drain
//      instead of after full-barrier resolution + tid0 wakeup.
// Claim/ticket logic and flag polling are byte-identical to R4 (proven).
__global__ __launch_bounds__(512, 1) void k_recur(
        const u16* __restrict__ tokbuf, const float* __restrict__ Gx,
        const u16* __restrict__ Bf, u16* __restrict__ Ax,
        int* __restrict__ bar) {
    __shared__ uint4 AhV[2][2048];        // 2 x 32 KB h slab (frag layout)
    __shared__ int sh_info;
    int tid = threadIdx.x;

    // ---- claim an XCD-local worker slot (proven in R4) ----
    if (tid == 0) {
        u32 xcc = 0;
        asm volatile("s_getreg_b32 %0, hwreg(HW_REG_XCC_ID)" : "=s"(xcc));
        xcc &= 7u;
        int t = -1;
        if (xcc < 2u) {
            int tk = __hip_atomic_fetch_add(bar + (int)xcc * 512, 1,
                         __ATOMIC_RELAXED, __HIP_MEMORY_SCOPE_AGENT);
            if (tk < 32) t = ((int)xcc << 5) | tk;
        }
        sh_info = t;
    }
    __syncthreads();
    int info = sh_info;
    if (info < 0) return;                 // not a worker
    int mt = info >> 5;                   // group == physical XCD (0 or 1)
    int p  = info & 31;                   // producer index [0,32)

    int w = tid >> 6, L = tid & 63;
    int nt = p * 8 + w;                   // [0,256)
    int lm = L & 15, quad = L >> 4;

    // W_hh A-fragments -> registers
    s16x8 afr[32];
    {
        const u16* bfp = Bf + (size_t)nt * 16384 + L * 8;
        #pragma unroll
        for (int kc = 0; kc < 32; ++kc)
            afr[kc] = *reinterpret_cast<const s16x8*>(bfp + kc * 512);
    }
    int jg = nt * 4 + quad;               // this lane's output column
    int b = mt * 16 + lm;                 // this lane's batch
    const float* gxp = Gx + (size_t)jg * 56;
    u32 posu16 = (u32)((nt >> 3) * 512 + ((lm | (((nt >> 1) & 3) << 4)) << 3)
                       + (nt & 1) * 4 + quad);
    int* flags = bar + mt * 512 + 16;     // flag(p) at +p*8; counter at +p*8+4
    int* cntp  = flags + p * 8 + 4;       // this block's drain counter
    int* flagout = flags + p * 8;         // this block's flag
    u32* AxD = (u32*)Ax;
    float c = 0.f;

    for (int s = 0; s < T_; ++s) {
        // prefetch x-term (independent of slab)
        int tok = tokbuf[s * 32 + b];
        float4 gx4 = *reinterpret_cast<const float4*>(gxp + tok * 4);

        // per-chunk pipelined poll + stage into buf[s&1]:
        // wave w's load i covers exactly chunk i*8+w (thread tid stages
        // bytes [i*8KB + tid*16), chunk = 1KB). All lanes poll the SAME
        // flag dword (one broadcast L2 transaction), agent scope = L1-bypass,
        // serviced by the local L2.
        const uint4* srcq = (const uint4*)((const char*)Ax
                             + ((size_t)s * 2 + mt) * 32768);
        uint4* dstq = &AhV[s & 1][0];
        #pragma unroll
        for (int i = 0; i < 4; ++i) {
            const int* fp = flags + (i * 8 + w) * 8;
            for (;;) {
                int v = __hip_atomic_load(fp, __ATOMIC_RELAXED,
                                          __HIP_MEMORY_SCOPE_AGENT);
                if (v >= s) break;
                __builtin_amdgcn_s_sleep(1);
            }
            asm volatile("" ::: "memory");   // keep the load below the poll
            dstq[i * 512 + tid] = srcq[i * 512 + tid];
        }
        __syncthreads();                  // barrier #1: slab resident in LDS

        // gates tile: A = W frags (regs), B = h frags (LDS); 4 indep chains
        f32x4 a0 = {0.f,0.f,0.f,0.f}, a1 = {0.f,0.f,0.f,0.f};
        f32x4 a2 = {0.f,0.f,0.f,0.f}, a3 = {0.f,0.f,0.f,0.f};
        const u16* hp = (const u16*)dstq + L * 8;
        #pragma unroll
        for (int kc = 0; kc < 32; kc += 4) {
            s16x8 h0 = *reinterpret_cast<const s16x8*>(hp + kc * 512);
            s16x8 h1 = *reinterpret_cast<const s16x8*>(hp + (kc + 1) * 512);
            s16x8 h2 = *reinterpret_cast<const s16x8*>(hp + (kc + 2) * 512);
            s16x8 h3 = *reinterpret_cast<const s16x8*>(hp + (kc + 3) * 512);
            a0 = __builtin_amdgcn_mfma_f32_16x16x32_bf16(afr[kc],     h0, a0, 0, 0, 0);
            a1 = __builtin_amdgcn_mfma_f32_16x16x32_bf16(afr[kc + 1], h1, a1, 0, 0, 0);
            a2 = __builtin_amdgcn_mfma_f32_16x16x32_bf16(afr[kc + 2], h2, a2, 0, 0, 0);
            a3 = __builtin_amdgcn_mfma_f32_16x16x32_bf16(afr[kc + 3], h3, a3, 0, 0, 0);
        }
        // acc[r] = gate r (i,f,g,o) for (b, jg)
        float gi = a0[0] + a1[0] + a2[0] + a3[0] + gx4.x;
        float gf = a0[1] + a1[1] + a2[1] + a3[1] + gx4.y;
        float gg = a0[2] + a1[2] + a2[2] + a3[2] + gx4.z;
        float go = a0[3] + a1[3] + a2[3] + a3[3] + gx4.w;
        float ig = sigm_(gi), fg = sigm_(gf);
        float gt = tanh_(gg), og = sigm_(go);
        c = fg * c + ig * gt;
        float hv = og * tanh_(c);

        // write h(s+1): pack 2 bf16/dword, PLAIN store (dirty in local L2)
        u32 bits = (u32)f2bf(hv);
        u32 other = (u32)(u16)__shfl_xor((int)bits, 16);
        if (!(quad & 1)) {
            u32 word = bits | (other << 16);
            AxD[((size_t)(s + 1) * 2 + mt) * 8192 + (posu16 >> 1)] = word;
        }
        if (s == T_ - 1) break;           // final slab drains at kernel end

        // early publish: drain OWN stores (acks at local L2), count drained
        // waves; the 8th publishes the single per-block flag (R4 coarse
        // granularity). Within-block counter: workgroup scope, same CU.
        asm volatile("s_waitcnt vmcnt(0)" ::: "memory");
        if (L == 0) {
            int old = __hip_atomic_fetch_add(cntp, 1, __ATOMIC_RELAXED,
                                             __HIP_MEMORY_SCOPE_WORKGROUP);
            if (old == 8 * s + 7)
                __hip_atomic_store(flagout, s + 1, __ATOMIC_RELAXED,
                                   __HIP_MEMORY_SCOPE_AGENT);
        }
        // no barrier #2: double-buffered LDS (see WAR proof above)
    }
}

// ---------------------------------------------------------------------------
// mid = relu(feat @ Wnl^T + bnl) — A/B frags straight from global, no LDS.
__global__ __launch_bounds__(256) void k_gemm1(
        const u16* __restrict__ Ax, const u16* __restrict__ Az,
        const u16* __restrict__ Bf2, const float* __restrict__ bnl,
        u16* __restrict__ mid) {
    int tid = threadIdx.x;
    int nb = blockIdx.x;                  // [0,16)
    int mb = blockIdx.y;                  // [0,128)
    int w = tid >> 6, L = tid & 63;
    int lm = L & 15, quad = L >> 4;
    int mti0 = mb * 8 + w * 2;
    const u16* a0p = Ax + ((size_t)mti0 + 2) * 16384 + L * 8;
    const u16* a1p = a0p + 16384;
    const u16* az0 = Az + L * 8;
    const u16* az1 = az0 + 4096;
    const u16* bp = Bf2 + (size_t)(nb * 4) * 40 * 512 + L * 8;

    f32x4 acc[2][4];
    #pragma unroll
    for (int a = 0; a < 2; ++a)
        #pragma unroll
        for (int n = 0; n < 4; ++n) acc[a][n] = (f32x4){0.f, 0.f, 0.f, 0.f};

    #pragma unroll 4
    for (int kc = 0; kc < 32; ++kc) {
        s16x8 a0 = *reinterpret_cast<const s16x8*>(a0p + kc * 512);
        s16x8 a1 = *reinterpret_cast<const s16x8*>(a1p + kc * 512);
        #pragma unroll
        for (int n4 = 0; n4 < 4; ++n4) {
            s16x8 bv = *reinterpret_cast<const s16x8*>(bp + ((size_t)n4 * 40 + kc) * 512);
            acc[0][n4] = __builtin_amdgcn_mfma_f32_16x16x32_bf16(a0, bv, acc[0][n4], 0, 0, 0);
            acc[1][n4] = __builtin_amdgcn_mfma_f32_16x16x32_bf16(a1, bv, acc[1][n4], 0, 0, 0);
        }
    }
    #pragma unroll
    for (int kc2 = 0; kc2 < 8; ++kc2) {
        s16x8 a0 = *reinterpret_cast<const s16x8*>(az0 + kc2 * 512);
        s16x8 a1 = *reinterpret_cast<const s16x8*>(az1 + kc2 * 512);
        #pragma unroll
        for (int n4 = 0; n4 < 4; ++n4) {
            s16x8 bv = *reinterpret_cast<const s16x8*>(bp + ((size_t)n4 * 40 + 32 + kc2) * 512);
            acc[0][n4] = __builtin_amdgcn_mfma_f32_16x16x32_bf16(a0, bv, acc[0][n4], 0, 0, 0);
            acc[1][n4] = __builtin_amdgcn_mfma_f32_16x16x32_bf16(a1, bv, acc[1][n4], 0, 0, 0);
        }
    }
    #pragma unroll
    for (int mt2 = 0; mt2 < 2; ++mt2)
        #pragma unroll
        for (int n4 = 0; n4 < 4; ++n4)
            #pragma unroll
            for (int r = 0; r < 4; ++r) {
                int m = mb * 128 + w * 32 + mt2 * 16 + quad * 4 + r;
                int n = (nb * 4 + n4) * 16 + lm;
                float v = acc[mt2][n4][r] + bnl[n];
                mid[(size_t)m * H_ + n] = f2bf(fmaxf(v, 0.f));
            }
}

// ---------------------------------------------------------------------------
__global__ __launch_bounds__(256) void k_loss(
        const u16* __restrict__ mid, const float* __restrict__ Wout,
        const float* __restrict__ bout, const int* __restrict__ labels,
        const int* __restrict__ lengths, float* __restrict__ out) {
    int mrow = blockIdx.x;                // m = t*32 + b
    int b = mrow & 31, t = mrow >> 5;
    if (t >= lengths[b]) return;
    int tid = threadIdx.x;
    float p[V_];
    #pragma unroll
    for (int v = 0; v < V_; ++v) p[v] = 0.f;
    uint2 raw = *reinterpret_cast<const uint2*>(mid + (size_t)mrow * H_ + tid * 4);
    const u16* rs = (const u16*)&raw;
    float mv0 = bf2f(rs[0]), mv1 = bf2f(rs[1]), mv2 = bf2f(rs[2]), mv3 = bf2f(rs[3]);
    #pragma unroll
    for (int v = 0; v < V_; ++v) {
        float4 wv = *reinterpret_cast<const float4*>(Wout + v * H_ + tid * 4);
        p[v] = mv0 * wv.x + mv1 * wv.y + mv2 * wv.z + mv3 * wv.w;
    }
    #pragma unroll
    for (int off = 32; off > 0; off >>= 1)
        #pragma unroll
        for (int v = 0; v < V_; ++v) p[v] += __shfl_down(p[v], off);
    __shared__ float red[4][V_];
    int w = tid >> 6, L = tid & 63;
    if (L == 0)
        #pragma unroll
        for (int v = 0; v < V_; ++v) red[w][v] = p[v];
    __syncthreads();
    if (tid == 0) {
        float lg[V_]; float mx = -1e30f;
        #pragma unroll
        for (int v = 0; v < V_; ++v) {
            lg[v] = red[0][v] + red[1][v] + red[2][v] + red[3][v] + bout[v];
            mx = fmaxf(mx, lg[v]);
        }
        float se = 0.f;
        #pragma unroll
        for (int v = 0; v < V_; ++v) se += __expf(lg[v] - mx);
        float lse = mx + logf(se);
        int lab = labels[b * T_ + t];
        atomicAdd(&out[1 + b], lse - lg[lab]);
    }
}

__global__ void k_final(float* __restrict__ out) {
    float s = 0.f;
    for (int b = 0; b < B_; ++b) s += out[1 + b];
    out[0] = s;
}

// ---------------------------------------------------------------------------
extern "C" void kernel_launch(void* const* d_in, const int* in_sizes, int n_in,
                              void* d_out, int out_size, void* d_ws, size_t ws_size,
                              hipStream_t stream) {
    const float* seq    = (const float*)d_in[0];
    const float* latent = (const float*)d_in[1];
    const int*   labels = (const int*)d_in[2];
    const int*   lengths= (const int*)d_in[3];
    const float* W_ih   = (const float*)d_in[4];
    const float* W_hh   = (const float*)d_in[5];
    const float* b_ih   = (const float*)d_in[6];
    const float* b_hh   = (const float*)d_in[7];
    const float* Wz     = (const float*)d_in[8];
    const float* bz     = (const float*)d_in[9];
    const float* Wnl    = (const float*)d_in[10];
    const float* bnl    = (const float*)d_in[11];
    const float* Wout   = (const float*)d_in[12];
    const float* bout   = (const float*)d_in[13];

    char* ws = (char*)d_ws;
    u16*   Ax   = (u16*)(ws);
    u16*   Bf   = (u16*)(ws + OFF_BF);
    u16*   Bf2  = (u16*)(ws + OFF_BF2);
    u16*   Az   = (u16*)(ws + OFF_AZ);
    int*   bar  = (int*)(ws + OFF_BAR);
    u16*   mid  = (u16*)(ws + OFF_MID);
    float* Gx   = (float*)(ws + OFF_GX);
    u16*   tok  = (u16*)(ws + OFF_TOK);
    float* out  = (float*)d_out;

    hipMemsetAsync(d_out, 0, 33 * sizeof(float), stream);
    k_init_misc<<<128, 256, 0, stream>>>(latent, Wz, bz, Ax, Az, bar);
    k_init_gx<<<16, 256, 0, stream>>>(W_ih, b_ih, b_hh, Gx);
    k_init_tok<<<64, 256, 0, stream>>>(seq, tok);
    k_init_wfrag<<<2048, 256, 0, stream>>>(W_hh, Bf);
    k_init_wfrag2<<<2048, 256, 0, stream>>>(Wnl, Bf2);
    k_recur<<<512, 512, 0, stream>>>(tok, Gx, Bf, Ax, bar);
    k_gemm1<<<dim3(16, 128), 256, 0, stream>>>(Ax, Az, Bf2, bnl, mid);
    k_loss<<<16384, 256, 0, stream>>>(mid, Wout, bout, labels, lengths, out);
    k_final<<<1, 1, 0, stream>>>(out);
}

// Round 9
// 1250.966 us; speedup vs baseline: 2.7174x; 1.8705x over previous
//
#include <hip/hip_runtime.h>
#include <hip/hip_bf16.h>

#define B_   32
#define T_   512
#define H_   1024
#define L_   256
#define V_   13
#define G4H  4096
#define KHL  1280   // H + L

typedef float f32x4 __attribute__((ext_vector_type(4)));
typedef short s16x8 __attribute__((ext_vector_type(8)));
typedef unsigned short u16;
typedef unsigned int   u32;
typedef unsigned long long u64;

// ---------------- ws layout (bytes) ----------------
// Ax  : u16 [1026][16384]    @ 0           (33,619,968)  h chain, MFMA frag layout
//        slab (s,mt) at (s*2+mt)*32768 B; producer p's data = 1KB chunk p
// Bf  : u16 [4,194,304]      @ 33,619,968  (8,388,608)   W_hh A-fragments
// Bf2 : u16 [1,310,720]      @ 42,008,576  (2,621,440)   Wnl  B-fragments
// Az  : u16 [2][4096]        @ 44,630,016  (16,384)      latent frag layout
// bar : int [2][512]         @ 44,646,400  (4,096)
//        group mt: ticket counter at bar[mt*512] (own 64B line);
//        flags at bar[mt*512 + 16 + p*8] (32B stride, p in [0,32))
// mid : u16 [16384][1024]    @ 44,650,496  (33,554,432)
//   Gx (f32[57344]) and tok (u16[16384]) overlay mid (read only in k_recur).
#define OFF_BF   33619968u
#define OFF_BF2  42008576u
#define OFF_AZ   44630016u
#define OFF_BAR  44646400u
#define OFF_MID  44650496u
#define OFF_GX   OFF_MID                  // 229,376 B  = [jg][14][4] f32
#define OFF_TOK  (OFF_MID + 229376u)      //  32,768 B

__device__ __forceinline__ u16 f2bf(float f) {
    union { float f; u32 u; } v; v.f = f;
    u32 u = v.u;
    u32 r = (u + 0x7fffu + ((u >> 16) & 1u)) >> 16;   // RNE
    return (u16)r;
}
__device__ __forceinline__ float bf2f(u16 h) {
    union { u32 u; float f; } v; v.u = ((u32)h) << 16;
    return v.f;
}
__device__ __forceinline__ float sigm_(float x) {
    x = fminf(fmaxf(x, -30.f), 30.f);
    return 1.f / (1.f + __expf(-x));
}
__device__ __forceinline__ float tanh_(float x) {
    x = fminf(fmaxf(x, -15.f), 15.f);
    float e = __expf(2.f * x);
    return (e - 1.f) / (e + 1.f);
}

// fragment position of (lane-dim index bl, k) within a 16384-u16 slab
__device__ __forceinline__ u32 afrag_pos(int bl, int k) {
    return (u32)((k >> 5) * 512 + ((bl | (((k >> 3) & 3) << 4)) << 3) + (k & 7));
}

// ---------------------------------------------------------------------------
__global__ __launch_bounds__(256) void k_init_misc(
        const float* __restrict__ latent, const float* __restrict__ Wz,
        const float* __restrict__ bz,
        u16* __restrict__ Ax, u16* __restrict__ Az, int* __restrict__ bar) {
    int gid = blockIdx.x * 256 + threadIdx.x;          // [0, 32768)
    int b = gid >> 10, j = gid & 1023;
    const float* lrow = latent + b * L_;
    const float* wrow = Wz + j * L_;
    float acc = bz[j];
    #pragma unroll 4
    for (int l = 0; l < L_; ++l) acc += lrow[l] * wrow[l];
    Ax[(b >> 4) * 16384 + afrag_pos(b & 15, j)] = f2bf(fmaxf(acc, 0.f));
    if (gid < B_ * L_) {
        int bb = gid >> 8, l = gid & 255;
        Az[(bb >> 4) * 4096 + afrag_pos(bb & 15, l)] = f2bf(latent[gid]);
    }
    if (gid < 1024) bar[gid] = 0;
}

// Gx[jg][t][gg] (t in [0,14), gg gate): W_ih[gg*H+jg][t] + b_ih + b_hh ; t=13 -> bias only
__global__ __launch_bounds__(256) void k_init_gx(
        const float* __restrict__ W_ih, const float* __restrict__ b_ih,
        const float* __restrict__ b_hh, float* __restrict__ Gx) {
    int row = blockIdx.x * 256 + threadIdx.x;          // [0,4096)
    if (row >= G4H) return;
    int gg = row >> 10, jg = row & 1023;
    float base = b_ih[row] + b_hh[row];
    float* d = Gx + (size_t)jg * 56;
    const float* wr = W_ih + (size_t)row * V_;
    #pragma unroll
    for (int t = 0; t < V_; ++t) d[t * 4 + gg] = base + wr[t];
    d[13 * 4 + gg] = base;
}

// tok[s*32+b] = one-hot index of seq[b,s,:] (13 if all-zero start row)
__global__ __launch_bounds__(256) void k_init_tok(
        const float* __restrict__ seq, u16* __restrict__ tok) {
    int gid = blockIdx.x * 256 + threadIdx.x;          // [0,16384)
    int s = gid >> 5, b = gid & 31;
    const float* r = seq + ((size_t)b * T_ + s) * V_;
    int t = 13;
    #pragma unroll
    for (int v = 0; v < V_; ++v) if (r[v] > 0.5f) t = v;
    tok[gid] = (u16)t;
}

// W_hh -> MFMA A-fragments. Tile col u = jj*4 + gate.
__global__ __launch_bounds__(256) void k_init_wfrag(
        const float* __restrict__ W_hh, u16* __restrict__ Bf) {
    int base = blockIdx.x * 256 + threadIdx.x;         // 2048 blocks
    #pragma unroll
    for (int i = 0; i < 8; ++i) {
        int idx = base + i * 524288;                   // [0, 4194304)
        int jv   = idx & 7;
        int lane = (idx >> 3) & 63;
        int kc   = (idx >> 9) & 31;
        int nt   = idx >> 14;
        int u = lane & 15;
        int row = (u & 3) * H_ + nt * 4 + (u >> 2);
        int k = kc * 32 + (lane >> 4) * 8 + jv;
        Bf[idx] = f2bf(W_hh[row * H_ + k]);
    }
}

__global__ __launch_bounds__(256) void k_init_wfrag2(
        const float* __restrict__ Wnl, u16* __restrict__ Bf2) {
    int idx = blockIdx.x * 256 + threadIdx.x;
    for (; idx < 1310720; idx += 524288) {
        int jv   = idx & 7;
        int lane = (idx >> 3) & 63;
        int q    = idx >> 9;                           // nt2*40 + kc
        int kc   = q % 40;
        int nt2  = q / 40;
        int n = nt2 * 16 + (lane & 15);
        int k = kc * 32 + (lane >> 4) * 8 + jv;
        Bf2[idx] = f2bf(Wnl[n * KHL + k]);
    }
}

// ---------------------------------------------------------------------------
// Persistent LSTM recurrence, XCD-local exchange. Sync structure is
// byte-identical to the proven R4 kernel (2 barriers, tid0 publish, coarse
// per-block flags, agent-scope polls, plain L2 stores) — R5..R8 showed every
// deviation from this lockstep regresses.
// MICRO-OPT vs R4: wave w stages the CONTIGUOUS chunks {4w..4w+3}; chunk c
// is exactly K-slice kc=c, and lane L's staged 16B is exactly its MFMA
// B-fragment for kc=c. The 4 staged fragments are kept in registers and
// their 4 MFMAs issue BEFORE barrier #1 (no LDS dependency -> overlaps other
// waves' staging); after the barrier only the remaining 28 kc are read from
// LDS. Per-CU LDS reads drop 256KB -> 224KB/step. switch(w) specializations
// keep every afr/st index compile-time constant (no scratch, no runtime
// branches in the MFMA loop).
__global__ __launch_bounds__(512, 1) void k_recur(
        const u16* __restrict__ tokbuf, const float* __restrict__ Gx,
        const u16* __restrict__ Bf, u16* __restrict__ Ax,
        int* __restrict__ bar) {
    __shared__ uint4 AhV[2048];           // 32 KB h slab (frag layout)
    __shared__ int sh_info;
    int tid = threadIdx.x;

    // ---- claim an XCD-local worker slot (proven in R4) ----
    if (tid == 0) {
        u32 xcc = 0;
        asm volatile("s_getreg_b32 %0, hwreg(HW_REG_XCC_ID)" : "=s"(xcc));
        xcc &= 7u;
        int t = -1;
        if (xcc < 2u) {
            int tk = __hip_atomic_fetch_add(bar + (int)xcc * 512, 1,
                         __ATOMIC_RELAXED, __HIP_MEMORY_SCOPE_AGENT);
            if (tk < 32) t = ((int)xcc << 5) | tk;
        }
        sh_info = t;
    }
    __syncthreads();
    int info = sh_info;
    if (info < 0) return;                 // not a worker
    int mt = info >> 5;                   // group == physical XCD (0 or 1)
    int p  = info & 31;                   // producer index [0,32)

    int w = tid >> 6, L = tid & 63;
    int nt = p * 8 + w;                   // [0,256)
    int lm = L & 15, quad = L >> 4;

    // W_hh A-fragments -> registers
    s16x8 afr[32];
    {
        const u16* bfp = Bf + (size_t)nt * 16384 + L * 8;
        #pragma unroll
        for (int kc = 0; kc < 32; ++kc)
            afr[kc] = *reinterpret_cast<const s16x8*>(bfp + kc * 512);
    }
    int jg = nt * 4 + quad;               // this lane's output column
    int b = mt * 16 + lm;                 // this lane's batch
    const float* gxp = Gx + (size_t)jg * 56;
    u32 posu16 = (u32)((nt >> 3) * 512 + ((lm | (((nt >> 1) & 3) << 4)) << 3)
                       + (nt & 1) * 4 + quad);
    int* flags = bar + mt * 512 + 16;     // 32 flags, stride 8 dwords (32 B)
    // wave w stages chunks {4w+i}; lane L polls chunk 4w+(L&3)
    const int* myflag = flags + (4 * w + (L & 3)) * 8;
    u32* AxD = (u32*)Ax;
    float c = 0.f;

    for (int s = 0; s < T_; ++s) {
        // prefetch x-term (independent of slab)
        int tok = tokbuf[s * 32 + b];
        float4 gx4 = *reinterpret_cast<const float4*>(gxp + tok * 4);

        // wave-local: wait for this wave's 4 staging producers (blocks 4w..4w+3)
        for (;;) {
            int v = __hip_atomic_load(myflag, __ATOMIC_RELAXED,
                                      __HIP_MEMORY_SCOPE_AGENT);
            if (__all(v >= s)) break;
            __builtin_amdgcn_s_sleep(1);
        }
        asm volatile("" ::: "memory");    // keep staging loads below the poll

        // stage chunks {4w+i} (contiguous 4KB per wave) with cacheable 16B
        // loads (write-once addresses; flags order visibility; local-L2 hits).
        // st[i] = lane L's B-fragment for kc = 4w+i (layout identity).
        const uint4* srcq = (const uint4*)((const char*)Ax
                             + ((size_t)s * 2 + mt) * 32768);
        s16x8 st[4];
        #pragma unroll
        for (int i = 0; i < 4; ++i)
            st[i] = *reinterpret_cast<const s16x8*>(srcq + (4 * w + i) * 64 + L);
        #pragma unroll
        for (int i = 0; i < 4; ++i)
            AhV[(4 * w + i) * 64 + L] = *reinterpret_cast<const uint4*>(&st[i]);

        // pre-barrier MFMAs on own staged fragments (kc = 4w+i, chain i)
        f32x4 a0 = {0.f,0.f,0.f,0.f}, a1 = {0.f,0.f,0.f,0.f};
        f32x4 a2 = {0.f,0.f,0.f,0.f}, a3 = {0.f,0.f,0.f,0.f};
        #define OWN_MFMA(WW) \
            a0 = __builtin_amdgcn_mfma_f32_16x16x32_bf16(afr[4*(WW)+0], st[0], a0, 0, 0, 0); \
            a1 = __builtin_amdgcn_mfma_f32_16x16x32_bf16(afr[4*(WW)+1], st[1], a1, 0, 0, 0); \
            a2 = __builtin_amdgcn_mfma_f32_16x16x32_bf16(afr[4*(WW)+2], st[2], a2, 0, 0, 0); \
            a3 = __builtin_amdgcn_mfma_f32_16x16x32_bf16(afr[4*(WW)+3], st[3], a3, 0, 0, 0);
        switch (w) {
            case 0: OWN_MFMA(0) break;  case 1: OWN_MFMA(1) break;
            case 2: OWN_MFMA(2) break;  case 3: OWN_MFMA(3) break;
            case 4: OWN_MFMA(4) break;  case 5: OWN_MFMA(5) break;
            case 6: OWN_MFMA(6) break;  default: OWN_MFMA(7) break;
        }
        #undef OWN_MFMA
        __syncthreads();                  // barrier 1: whole slab in LDS

        // remaining 28 kc from LDS (skip own 4; all indices compile-time)
        const u16* hp = (const u16*)AhV + L * 8;
        #define KC_LOOP(WW) \
            _Pragma("unroll") \
            for (int kc = 0; kc < 32; ++kc) { \
                if ((kc >> 2) == (WW)) continue; \
                s16x8 h = *reinterpret_cast<const s16x8*>(hp + kc * 512); \
                if ((kc & 3) == 0)      a0 = __builtin_amdgcn_mfma_f32_16x16x32_bf16(afr[kc], h, a0, 0, 0, 0); \
                else if ((kc & 3) == 1) a1 = __builtin_amdgcn_mfma_f32_16x16x32_bf16(afr[kc], h, a1, 0, 0, 0); \
                else if ((kc & 3) == 2) a2 = __builtin_amdgcn_mfma_f32_16x16x32_bf16(afr[kc], h, a2, 0, 0, 0); \
                else                    a3 = __builtin_amdgcn_mfma_f32_16x16x32_bf16(afr[kc], h, a3, 0, 0, 0); \
            }
        switch (w) {
            case 0: KC_LOOP(0) break;  case 1: KC_LOOP(1) break;
            case 2: KC_LOOP(2) break;  case 3: KC_LOOP(3) break;
            case 4: KC_LOOP(4) break;  case 5: KC_LOOP(5) break;
            case 6: KC_LOOP(6) break;  default: KC_LOOP(7) break;
        }
        #undef KC_LOOP

        // acc[r] = gate r (i,f,g,o) for (b, jg)
        float gi = a0[0] + a1[0] + a2[0] + a3[0] + gx4.x;
        float gf = a0[1] + a1[1] + a2[1] + a3[1] + gx4.y;
        float gg = a0[2] + a1[2] + a2[2] + a3[2] + gx4.z;
        float go = a0[3] + a1[3] + a2[3] + a3[3] + gx4.w;
        float ig = sigm_(gi), fg = sigm_(gf);
        float gt = tanh_(gg), og = sigm_(go);
        c = fg * c + ig * gt;
        float hv = og * tanh_(c);

        // write h(s+1): pack 2 bf16/dword, PLAIN store (dirty in local L2;
        // the only in-kernel consumers share this XCD's L2)
        u32 bits = (u32)f2bf(hv);
        u32 other = (u32)(u16)__shfl_xor((int)bits, 16);
        if (!(quad & 1)) {
            u32 word = bits | (other << 16);
            AxD[((size_t)(s + 1) * 2 + mt) * 8192 + (posu16 >> 1)] = word;
        }
        if (s == T_ - 1) break;           // final slab drains at kernel end
        __syncthreads();                  // barrier 2: all h stores in L2
        if (tid == 0)                     // publish chunk p of slab s+1
            __hip_atomic_store(flags + p * 8, s + 1, __ATOMIC_RELAXED,
                               __HIP_MEMORY_SCOPE_WORKGROUP);
    }
}

// ---------------------------------------------------------------------------
// mid = relu(feat @ Wnl^T + bnl) — A/B frags straight from global, no LDS.
__global__ __launch_bounds__(256) void k_gemm1(
        const u16* __restrict__ Ax, const u16* __restrict__ Az,
        const u16* __restrict__ Bf2, const float* __restrict__ bnl,
        u16* __restrict__ mid) {
    int tid = threadIdx.x;
    int nb = blockIdx.x;                  // [0,16)
    int mb = blockIdx.y;                  // [0,128)
    int w = tid >> 6, L = tid & 63;
    int lm = L & 15, quad = L >> 4;
    int mti0 = mb * 8 + w * 2;
    const u16* a0p = Ax + ((size_t)mti0 + 2) * 16384 + L * 8;
    const u16* a1p = a0p + 16384;
    const u16* az0 = Az + L * 8;
    const u16* az1 = az0 + 4096;
    const u16* bp = Bf2 + (size_t)(nb * 4) * 40 * 512 + L * 8;

    f32x4 acc[2][4];
    #pragma unroll
    for (int a = 0; a < 2; ++a)
        #pragma unroll
        for (int n = 0; n < 4; ++n) acc[a][n] = (f32x4){0.f, 0.f, 0.f, 0.f};

    #pragma unroll 4
    for (int kc = 0; kc < 32; ++kc) {
        s16x8 a0 = *reinterpret_cast<const s16x8*>(a0p + kc * 512);
        s16x8 a1 = *reinterpret_cast<const s16x8*>(a1p + kc * 512);
        #pragma unroll
        for (int n4 = 0; n4 < 4; ++n4) {
            s16x8 bv = *reinterpret_cast<const s16x8*>(bp + ((size_t)n4 * 40 + kc) * 512);
            acc[0][n4] = __builtin_amdgcn_mfma_f32_16x16x32_bf16(a0, bv, acc[0][n4], 0, 0, 0);
            acc[1][n4] = __builtin_amdgcn_mfma_f32_16x16x32_bf16(a1, bv, acc[1][n4], 0, 0, 0);
        }
    }
    #pragma unroll
    for (int kc2 = 0; kc2 < 8; ++kc2) {
        s16x8 a0 = *reinterpret_cast<const s16x8*>(az0 + kc2 * 512);
        s16x8 a1 = *reinterpret_cast<const s16x8*>(az1 + kc2 * 512);
        #pragma unroll
        for (int n4 = 0; n4 < 4; ++n4) {
            s16x8 bv = *reinterpret_cast<const s16x8*>(bp + ((size_t)n4 * 40 + 32 + kc2) * 512);
            acc[0][n4] = __builtin_amdgcn_mfma_f32_16x16x32_bf16(a0, bv, acc[0][n4], 0, 0, 0);
            acc[1][n4] = __builtin_amdgcn_mfma_f32_16x16x32_bf16(a1, bv, acc[1][n4], 0, 0, 0);
        }
    }
    #pragma unroll
    for (int mt2 = 0; mt2 < 2; ++mt2)
        #pragma unroll
        for (int n4 = 0; n4 < 4; ++n4)
            #pragma unroll
            for (int r = 0; r < 4; ++r) {
                int m = mb * 128 + w * 32 + mt2 * 16 + quad * 4 + r;
                int n = (nb * 4 + n4) * 16 + lm;
                float v = acc[mt2][n4][r] + bnl[n];
                mid[(size_t)m * H_ + n] = f2bf(fmaxf(v, 0.f));
            }
}

// ---------------------------------------------------------------------------
__global__ __launch_bounds__(256) void k_loss(
        const u16* __restrict__ mid, const float* __restrict__ Wout,
        const float* __restrict__ bout, const int* __restrict__ labels,
        const int* __restrict__ lengths, float* __restrict__ out) {
    int mrow = blockIdx.x;                // m = t*32 + b
    int b = mrow & 31, t = mrow >> 5;
    if (t >= lengths[b]) return;
    int tid = threadIdx.x;
    float p[V_];
    #pragma unroll
    for (int v = 0; v < V_; ++v) p[v] = 0.f;
    uint2 raw = *reinterpret_cast<const uint2*>(mid + (size_t)mrow * H_ + tid * 4);
    const u16* rs = (const u16*)&raw;
    float mv0 = bf2f(rs[0]), mv1 = bf2f(rs[1]), mv2 = bf2f(rs[2]), mv3 = bf2f(rs[3]);
    #pragma unroll
    for (int v = 0; v < V_; ++v) {
        float4 wv = *reinterpret_cast<const float4*>(Wout + v * H_ + tid * 4);
        p[v] = mv0 * wv.x + mv1 * wv.y + mv2 * wv.z + mv3 * wv.w;
    }
    #pragma unroll
    for (int off = 32; off > 0; off >>= 1)
        #pragma unroll
        for (int v = 0; v < V_; ++v) p[v] += __shfl_down(p[v], off);
    __shared__ float red[4][V_];
    int w = tid >> 6, L = tid & 63;
    if (L == 0)
        #pragma unroll
        for (int v = 0; v < V_; ++v) red[w][v] = p[v];
    __syncthreads();
    if (tid == 0) {
        float lg[V_]; float mx = -1e30f;
        #pragma unroll
        for (int v = 0; v < V_; ++v) {
            lg[v] = red[0][v] + red[1][v] + red[2][v] + red[3][v] + bout[v];
            mx = fmaxf(mx, lg[v]);
        }
        float se = 0.f;
        #pragma unroll
        for (int v = 0; v < V_; ++v) se += __expf(lg[v] - mx);
        float lse = mx + logf(se);
        int lab = labels[b * T_ + t];
        atomicAdd(&out[1 + b], lse - lg[lab]);
    }
}

__global__ void k_final(float* __restrict__ out) {
    float s = 0.f;
    for (int b = 0; b < B_; ++b) s += out[1 + b];
    out[0] = s;
}

// ---------------------------------------------------------------------------
extern "C" void kernel_launch(void* const* d_in, const int* in_sizes, int n_in,
                              void* d_out, int out_size, void* d_ws, size_t ws_size,
                              hipStream_t stream) {
    const float* seq    = (const float*)d_in[0];
    const float* latent = (const float*)d_in[1];
    const int*   labels = (const int*)d_in[2];
    const int*   lengths= (const int*)d_in[3];
    const float* W_ih   = (const float*)d_in[4];
    const float* W_hh   = (const float*)d_in[5];
    const float* b_ih   = (const float*)d_in[6];
    const float* b_hh   = (const float*)d_in[7];
    const float* Wz     = (const float*)d_in[8];
    const float* bz     = (const float*)d_in[9];
    const float* Wnl    = (const float*)d_in[10];
    const float* bnl    = (const float*)d_in[11];
    const float* Wout   = (const float*)d_in[12];
    const float* bout   = (const float*)d_in[13];

    char* ws = (char*)d_ws;
    u16*   Ax   = (u16*)(ws);
    u16*   Bf   = (u16*)(ws + OFF_BF);
    u16*   Bf2  = (u16*)(ws + OFF_BF2);
    u16*   Az   = (u16*)(ws + OFF_AZ);
    int*   bar  = (int*)(ws + OFF_BAR);
    u16*   mid  = (u16*)(ws + OFF_MID);
    float* Gx   = (float*)(ws + OFF_GX);
    u16*   tok  = (u16*)(ws + OFF_TOK);
    float* out  = (float*)d_out;

    hipMemsetAsync(d_out, 0, 33 * sizeof(float), stream);
    k_init_misc<<<128, 256, 0, stream>>>(latent, Wz, bz, Ax, Az, bar);
    k_init_gx<<<16, 256, 0, stream>>>(W_ih, b_ih, b_hh, Gx);
    k_init_tok<<<64, 256, 0, stream>>>(seq, tok);
    k_init_wfrag<<<2048, 256, 0, stream>>>(W_hh, Bf);
    k_init_wfrag2<<<2048, 256, 0, stream>>>(Wnl, Bf2);
    k_recur<<<512, 512, 0, stream>>>(tok, Gx, Bf, Ax, bar);
    k_gemm1<<<dim3(16, 128), 256, 0, stream>>>(Ax, Az, Bf2, bnl, mid);
    k_loss<<<16384, 256, 0, stream>>>(mid, Wout, bout, labels, lengths, out);
    k_final<<<1, 1, 0, stream>>>(out);
}

// Round 10
// 1192.734 us; speedup vs baseline: 2.8500x; 1.0488x over previous
//
#include <hip/hip_runtime.h>
#include <hip/hip_bf16.h>

#define B_   32
#define T_   512
#define H_   1024
#define L_   256
#define V_   13
#define G4H  4096
#define KHL  1280   // H + L

typedef float f32x4 __attribute__((ext_vector_type(4)));
typedef short s16x8 __attribute__((ext_vector_type(8)));
typedef unsigned short u16;
typedef unsigned int   u32;
typedef unsigned long long u64;

// ---------------- ws layout (bytes) ----------------
// Ax  : u16 [1026][16384]    @ 0           (33,619,968)  h chain, MFMA frag layout
//        slab (s,mt) at (s*2+mt)*32768 B; producer p's data = 1KB chunk p
// Bf  : u16 [4,194,304]      @ 33,619,968  (8,388,608)   W_hh A-fragments
// Bf2 : u16 [1,310,720]      @ 42,008,576  (2,621,440)   Wnl  B-fragments
// Az  : u16 [2][4096]        @ 44,630,016  (16,384)      latent frag layout
// bar : int [2][512]         @ 44,646,400  (4,096)
//        group mt: ticket counter at bar[mt*512] (own 64B line);
//        flags at bar[mt*512 + 16 + p*8] (32B stride, p in [0,32))
// mid : u16 [16384][1024]    @ 44,650,496  (33,554,432)
//   Gx (f32[57344]) and tok (u16[16384]) overlay mid (read only in k_recur).
#define OFF_BF   33619968u
#define OFF_BF2  42008576u
#define OFF_AZ   44630016u
#define OFF_BAR  44646400u
#define OFF_MID  44650496u
#define OFF_GX   OFF_MID                  // 229,376 B  = [jg][14][4] f32
#define OFF_TOK  (OFF_MID + 229376u)      //  32,768 B

__device__ __forceinline__ u16 f2bf(float f) {
    union { float f; u32 u; } v; v.f = f;
    u32 u = v.u;
    u32 r = (u + 0x7fffu + ((u >> 16) & 1u)) >> 16;   // RNE
    return (u16)r;
}
__device__ __forceinline__ float bf2f(u16 h) {
    union { u32 u; float f; } v; v.u = ((u32)h) << 16;
    return v.f;
}
__device__ __forceinline__ float sigm_(float x) {
    x = fminf(fmaxf(x, -30.f), 30.f);
    return 1.f / (1.f + __expf(-x));
}
__device__ __forceinline__ float tanh_(float x) {
    x = fminf(fmaxf(x, -15.f), 15.f);
    float e = __expf(2.f * x);
    return (e - 1.f) / (e + 1.f);
}

// fragment position of (lane-dim index bl, k) within a 16384-u16 slab
__device__ __forceinline__ u32 afrag_pos(int bl, int k) {
    return (u32)((k >> 5) * 512 + ((bl | (((k >> 3) & 3) << 4)) << 3) + (k & 7));
}

// ---------------------------------------------------------------------------
__global__ __launch_bounds__(256) void k_init_misc(
        const float* __restrict__ latent, const float* __restrict__ Wz,
        const float* __restrict__ bz,
        u16* __restrict__ Ax, u16* __restrict__ Az, int* __restrict__ bar) {
    int gid = blockIdx.x * 256 + threadIdx.x;          // [0, 32768)
    int b = gid >> 10, j = gid & 1023;
    const float* lrow = latent + b * L_;
    const float* wrow = Wz + j * L_;
    float acc = bz[j];
    #pragma unroll 4
    for (int l = 0; l < L_; ++l) acc += lrow[l] * wrow[l];
    Ax[(b >> 4) * 16384 + afrag_pos(b & 15, j)] = f2bf(fmaxf(acc, 0.f));
    if (gid < B_ * L_) {
        int bb = gid >> 8, l = gid & 255;
        Az[(bb >> 4) * 4096 + afrag_pos(bb & 15, l)] = f2bf(latent[gid]);
    }
    if (gid < 1024) bar[gid] = 0;
}

// Gx[jg][t][gg] (t in [0,14), gg gate): W_ih[gg*H+jg][t] + b_ih + b_hh ; t=13 -> bias only
__global__ __launch_bounds__(256) void k_init_gx(
        const float* __restrict__ W_ih, const float* __restrict__ b_ih,
        const float* __restrict__ b_hh, float* __restrict__ Gx) {
    int row = blockIdx.x * 256 + threadIdx.x;          // [0,4096)
    if (row >= G4H) return;
    int gg = row >> 10, jg = row & 1023;
    float base = b_ih[row] + b_hh[row];
    float* d = Gx + (size_t)jg * 56;
    const float* wr = W_ih + (size_t)row * V_;
    #pragma unroll
    for (int t = 0; t < V_; ++t) d[t * 4 + gg] = base + wr[t];
    d[13 * 4 + gg] = base;
}

// tok[s*32+b] = one-hot index of seq[b,s,:] (13 if all-zero start row)
__global__ __launch_bounds__(256) void k_init_tok(
        const float* __restrict__ seq, u16* __restrict__ tok) {
    int gid = blockIdx.x * 256 + threadIdx.x;          // [0,16384)
    int s = gid >> 5, b = gid & 31;
    const float* r = seq + ((size_t)b * T_ + s) * V_;
    int t = 13;
    #pragma unroll
    for (int v = 0; v < V_; ++v) if (r[v] > 0.5f) t = v;
    tok[gid] = (u16)t;
}

// W_hh -> MFMA A-fragments. Tile col u = jj*4 + gate.
__global__ __launch_bounds__(256) void k_init_wfrag(
        const float* __restrict__ W_hh, u16* __restrict__ Bf) {
    int base = blockIdx.x * 256 + threadIdx.x;         // 2048 blocks
    #pragma unroll
    for (int i = 0; i < 8; ++i) {
        int idx = base + i * 524288;                   // [0, 4194304)
        int jv   = idx & 7;
        int lane = (idx >> 3) & 63;
        int kc   = (idx >> 9) & 31;
        int nt   = idx >> 14;
        int u = lane & 15;
        int row = (u & 3) * H_ + nt * 4 + (u >> 2);
        int k = kc * 32 + (lane >> 4) * 8 + jv;
        Bf[idx] = f2bf(W_hh[row * H_ + k]);
    }
}

__global__ __launch_bounds__(256) void k_init_wfrag2(
        const float* __restrict__ Wnl, u16* __restrict__ Bf2) {
    int idx = blockIdx.x * 256 + threadIdx.x;
    for (; idx < 1310720; idx += 524288) {
        int jv   = idx & 7;
        int lane = (idx >> 3) & 63;
        int q    = idx >> 9;                           // nt2*40 + kc
        int kc   = q % 40;
        int nt2  = q / 40;
        int n = nt2 * 16 + (lane & 15);
        int k = kc * 32 + (lane >> 4) * 8 + jv;
        Bf2[idx] = f2bf(Wnl[n * KHL + k]);
    }
}

// ---------------------------------------------------------------------------
// Persistent LSTM recurrence, XCD-local exchange. 512 candidate blocks x 512
// thr; each block reads its physical XCD (HW_REG_XCC_ID) and claims a ticket
// with an AGENT-scope fetch_add (executes at LLC -> globally coherent). First
// 32 claimants on XCD0 become group mt=0, first 32 on XCD1 mt=1; all other
// blocks exit (losers exiting guarantees dispatch progress, no deadlock).
// Within a group, producers and consumers share ONE XCD = ONE L2:
//  - h-data stores are PLAIN stores -> write-through L1, dirty in the local
//    L2. __syncthreads' vmcnt(0) drain acks at L2 (~400cy) and orders
//    data-before-flag within that L2.
//  - flag polls are AGENT-scope atomic loads: bypass L1, serviced by the
//    local L2 when the line is dirty there; first poll falls through to LLC
//    zeros (k_init_misc's kernel-end flush).
//  - slab staging loads are plain cacheable -> dirty-L2 hits.
// Every per-step hop runs at local-L2 cost instead of LLC (~900cy RT).
// This exact 2-barrier lockstep + coarse per-block flag protocol is the
// verified optimum: per-wave flags (R7), counter early-publish (R8), K-split
// reduction (R5), 2-nt waves (R6), and pre-barrier own-chunk MFMA (R9) all
// regressed with identified mechanisms. Do not relax the lockstep.
// k_gemm1 sees the Ax chain via the standard end-of-kernel L2 writeback.
__global__ __launch_bounds__(512, 1) void k_recur(
        const u16* __restrict__ tokbuf, const float* __restrict__ Gx,
        const u16* __restrict__ Bf, u16* __restrict__ Ax,
        int* __restrict__ bar) {
    __shared__ uint4 AhV[2048];           // 32 KB h slab (frag layout)
    __shared__ int sh_info;
    int tid = threadIdx.x;

    // ---- claim an XCD-local worker slot ----
    if (tid == 0) {
        u32 xcc = 0;
        asm volatile("s_getreg_b32 %0, hwreg(HW_REG_XCC_ID)" : "=s"(xcc));
        xcc &= 7u;
        int t = -1;
        if (xcc < 2u) {
            int tk = __hip_atomic_fetch_add(bar + (int)xcc * 512, 1,
                         __ATOMIC_RELAXED, __HIP_MEMORY_SCOPE_AGENT);
            if (tk < 32) t = ((int)xcc << 5) | tk;
        }
        sh_info = t;
    }
    __syncthreads();
    int info = sh_info;
    if (info < 0) return;                 // not a worker
    int mt = info >> 5;                   // group == physical XCD (0 or 1)
    int p  = info & 31;                   // producer index [0,32)

    int w = tid >> 6, L = tid & 63;
    int nt = p * 8 + w;                   // [0,256)
    int lm = L & 15, quad = L >> 4;

    // W_hh A-fragments -> registers
    s16x8 afr[32];
    {
        const u16* bfp = Bf + (size_t)nt * 16384 + L * 8;
        #pragma unroll
        for (int kc = 0; kc < 32; ++kc)
            afr[kc] = *reinterpret_cast<const s16x8*>(bfp + kc * 512);
    }
    int jg = nt * 4 + quad;               // this lane's output column
    int b = mt * 16 + lm;                 // this lane's batch
    const float* gxp = Gx + (size_t)jg * 56;
    u32 posu16 = (u32)((nt >> 3) * 512 + ((lm | (((nt >> 1) & 3) << 4)) << 3)
                       + (nt & 1) * 4 + quad);
    int* flags = bar + mt * 512 + 16;     // 32 flags, stride 8 dwords (32 B)
    const int* myflag = flags + (w + 8 * (L & 3)) * 8;   // this wave's 4 flags
    u32* AxD = (u32*)Ax;
    float c = 0.f;

    for (int s = 0; s < T_; ++s) {
        // prefetch x-term (independent of slab)
        int tok = tokbuf[s * 32 + b];
        float4 gx4 = *reinterpret_cast<const float4*>(gxp + tok * 4);

        // wave-local: wait for this wave's 4 producers to publish slab s
        // (agent-scope load = L1-bypass; serviced by the local L2)
        for (;;) {
            int v = __hip_atomic_load(myflag, __ATOMIC_RELAXED,
                                      __HIP_MEMORY_SCOPE_AGENT);
            if (__all(v >= s)) break;
            __builtin_amdgcn_s_sleep(1);
        }
        // stage this wave's 4 chunks (i*8+w) with cacheable 16B loads
        // (write-once addresses; flags order visibility; local-L2 hits)
        const uint4* srcq = (const uint4*)((const char*)Ax
                             + ((size_t)s * 2 + mt) * 32768);
        #pragma unroll
        for (int i = 0; i < 4; ++i)
            AhV[i * 512 + tid] = srcq[i * 512 + tid];
        __syncthreads();                  // whole slab resident in LDS

        // gates tile: A = W frags (regs), B = h frags (LDS); 4 indep chains
        f32x4 a0 = {0.f,0.f,0.f,0.f}, a1 = {0.f,0.f,0.f,0.f};
        f32x4 a2 = {0.f,0.f,0.f,0.f}, a3 = {0.f,0.f,0.f,0.f};
        const u16* hp = (const u16*)AhV + L * 8;
        #pragma unroll
        for (int kc = 0; kc < 32; kc += 4) {
            s16x8 h0 = *reinterpret_cast<const s16x8*>(hp + kc * 512);
            s16x8 h1 = *reinterpret_cast<const s16x8*>(hp + (kc + 1) * 512);
            s16x8 h2 = *reinterpret_cast<const s16x8*>(hp + (kc + 2) * 512);
            s16x8 h3 = *reinterpret_cast<const s16x8*>(hp + (kc + 3) * 512);
            a0 = __builtin_amdgcn_mfma_f32_16x16x32_bf16(afr[kc],     h0, a0, 0, 0, 0);
            a1 = __builtin_amdgcn_mfma_f32_16x16x32_bf16(afr[kc + 1], h1, a1, 0, 0, 0);
            a2 = __builtin_amdgcn_mfma_f32_16x16x32_bf16(afr[kc + 2], h2, a2, 0, 0, 0);
            a3 = __builtin_amdgcn_mfma_f32_16x16x32_bf16(afr[kc + 3], h3, a3, 0, 0, 0);
        }
        // acc[r] = gate r (i,f,g,o) for (b, jg)
        float gi = a0[0] + a1[0] + a2[0] + a3[0] + gx4.x;
        float gf = a0[1] + a1[1] + a2[1] + a3[1] + gx4.y;
        float gg = a0[2] + a1[2] + a2[2] + a3[2] + gx4.z;
        float go = a0[3] + a1[3] + a2[3] + a3[3] + gx4.w;
        float ig = sigm_(gi), fg = sigm_(gf);
        float gt = tanh_(gg), og = sigm_(go);
        c = fg * c + ig * gt;
        float hv = og * tanh_(c);

        // write h(s+1): pack 2 bf16/dword, PLAIN store (dirty in local L2;
        // the only in-kernel consumers share this XCD's L2)
        u32 bits = (u32)f2bf(hv);
        u32 other = (u32)(u16)__shfl_xor((int)bits, 16);
        if (!(quad & 1)) {
            u32 word = bits | (other << 16);
            AxD[((size_t)(s + 1) * 2 + mt) * 8192 + (posu16 >> 1)] = word;
        }
        if (s == T_ - 1) break;           // final slab drains at kernel end
        __syncthreads();                  // vmcnt(0): all 8 waves' h in L2
        if (tid == 0)                     // publish chunk p of slab s+1
            __hip_atomic_store(flags + p * 8, s + 1, __ATOMIC_RELAXED,
                               __HIP_MEMORY_SCOPE_WORKGROUP);
    }
}

// ---------------------------------------------------------------------------
// mid = relu(feat @ Wnl^T + bnl) — A/B frags straight from global, no LDS.
__global__ __launch_bounds__(256) void k_gemm1(
        const u16* __restrict__ Ax, const u16* __restrict__ Az,
        const u16* __restrict__ Bf2, const float* __restrict__ bnl,
        u16* __restrict__ mid) {
    int tid = threadIdx.x;
    int nb = blockIdx.x;                  // [0,16)
    int mb = blockIdx.y;                  // [0,128)
    int w = tid >> 6, L = tid & 63;
    int lm = L & 15, quad = L >> 4;
    int mti0 = mb * 8 + w * 2;
    const u16* a0p = Ax + ((size_t)mti0 + 2) * 16384 + L * 8;
    const u16* a1p = a0p + 16384;
    const u16* az0 = Az + L * 8;
    const u16* az1 = az0 + 4096;
    const u16* bp = Bf2 + (size_t)(nb * 4) * 40 * 512 + L * 8;

    f32x4 acc[2][4];
    #pragma unroll
    for (int a = 0; a < 2; ++a)
        #pragma unroll
        for (int n = 0; n < 4; ++n) acc[a][n] = (f32x4){0.f, 0.f, 0.f, 0.f};

    #pragma unroll 4
    for (int kc = 0; kc < 32; ++kc) {
        s16x8 a0 = *reinterpret_cast<const s16x8*>(a0p + kc * 512);
        s16x8 a1 = *reinterpret_cast<const s16x8*>(a1p + kc * 512);
        #pragma unroll
        for (int n4 = 0; n4 < 4; ++n4) {
            s16x8 bv = *reinterpret_cast<const s16x8*>(bp + ((size_t)n4 * 40 + kc) * 512);
            acc[0][n4] = __builtin_amdgcn_mfma_f32_16x16x32_bf16(a0, bv, acc[0][n4], 0, 0, 0);
            acc[1][n4] = __builtin_amdgcn_mfma_f32_16x16x32_bf16(a1, bv, acc[1][n4], 0, 0, 0);
        }
    }
    #pragma unroll
    for (int kc2 = 0; kc2 < 8; ++kc2) {
        s16x8 a0 = *reinterpret_cast<const s16x8*>(az0 + kc2 * 512);
        s16x8 a1 = *reinterpret_cast<const s16x8*>(az1 + kc2 * 512);
        #pragma unroll
        for (int n4 = 0; n4 < 4; ++n4) {
            s16x8 bv = *reinterpret_cast<const s16x8*>(bp + ((size_t)n4 * 40 + 32 + kc2) * 512);
            acc[0][n4] = __builtin_amdgcn_mfma_f32_16x16x32_bf16(a0, bv, acc[0][n4], 0, 0, 0);
            acc[1][n4] = __builtin_amdgcn_mfma_f32_16x16x32_bf16(a1, bv, acc[1][n4], 0, 0, 0);
        }
    }
    #pragma unroll
    for (int mt2 = 0; mt2 < 2; ++mt2)
        #pragma unroll
        for (int n4 = 0; n4 < 4; ++n4)
            #pragma unroll
            for (int r = 0; r < 4; ++r) {
                int m = mb * 128 + w * 32 + mt2 * 16 + quad * 4 + r;
                int n = (nb * 4 + n4) * 16 + lm;
                float v = acc[mt2][n4][r] + bnl[n];
                mid[(size_t)m * H_ + n] = f2bf(fmaxf(v, 0.f));
            }
}

// ---------------------------------------------------------------------------
__global__ __launch_bounds__(256) void k_loss(
        const u16* __restrict__ mid, const float* __restrict__ Wout,
        const float* __restrict__ bout, const int* __restrict__ labels,
        const int* __restrict__ lengths, float* __restrict__ out) {
    int mrow = blockIdx.x;                // m = t*32 + b
    int b = mrow & 31, t = mrow >> 5;
    if (t >= lengths[b]) return;
    int tid = threadIdx.x;
    float p[V_];
    #pragma unroll
    for (int v = 0; v < V_; ++v) p[v] = 0.f;
    uint2 raw = *reinterpret_cast<const uint2*>(mid + (size_t)mrow * H_ + tid * 4);
    const u16* rs = (const u16*)&raw;
    float mv0 = bf2f(rs[0]), mv1 = bf2f(rs[1]), mv2 = bf2f(rs[2]), mv3 = bf2f(rs[3]);
    #pragma unroll
    for (int v = 0; v < V_; ++v) {
        float4 wv = *reinterpret_cast<const float4*>(Wout + v * H_ + tid * 4);
        p[v] = mv0 * wv.x + mv1 * wv.y + mv2 * wv.z + mv3 * wv.w;
    }
    #pragma unroll
    for (int off = 32; off > 0; off >>= 1)
        #pragma unroll
        for (int v = 0; v < V_; ++v) p[v] += __shfl_down(p[v], off);
    __shared__ float red[4][V_];
    int w = tid >> 6, L = tid & 63;
    if (L == 0)
        #pragma unroll
        for (int v = 0; v < V_; ++v) red[w][v] = p[v];
    __syncthreads();
    if (tid == 0) {
        float lg[V_]; float mx = -1e30f;
        #pragma unroll
        for (int v = 0; v < V_; ++v) {
            lg[v] = red[0][v] + red[1][v] + red[2][v] + red[3][v] + bout[v];
            mx = fmaxf(mx, lg[v]);
        }
        float se = 0.f;
        #pragma unroll
        for (int v = 0; v < V_; ++v) se += __expf(lg[v] - mx);
        float lse = mx + logf(se);
        int lab = labels[b * T_ + t];
        atomicAdd(&out[1 + b], lse - lg[lab]);
    }
}

__global__ void k_final(float* __restrict__ out) {
    float s = 0.f;
    for (int b = 0; b < B_; ++b) s += out[1 + b];
    out[0] = s;
}

// ---------------------------------------------------------------------------
extern "C" void kernel_launch(void* const* d_in, const int* in_sizes, int n_in,
                              void* d_out, int out_size, void* d_ws, size_t ws_size,
                              hipStream_t stream) {
    const float* seq    = (const float*)d_in[0];
    const float* latent = (const float*)d_in[1];
    const int*   labels = (const int*)d_in[2];
    const int*   lengths= (const int*)d_in[3];
    const float* W_ih   = (const float*)d_in[4];
    const float* W_hh   = (const float*)d_in[5];
    const float* b_ih   = (const float*)d_in[6];
    const float* b_hh   = (const float*)d_in[7];
    const float* Wz     = (const float*)d_in[8];
    const float* bz     = (const float*)d_in[9];
    const float* Wnl    = (const float*)d_in[10];
    const float* bnl    = (const float*)d_in[11];
    const float* Wout   = (const float*)d_in[12];
    const float* bout   = (const float*)d_in[13];

    char* ws = (char*)d_ws;
    u16*   Ax   = (u16*)(ws);
    u16*   Bf   = (u16*)(ws + OFF_BF);
    u16*   Bf2  = (u16*)(ws + OFF_BF2);
    u16*   Az   = (u16*)(ws + OFF_AZ);
    int*   bar  = (int*)(ws + OFF_BAR);
    u16*   mid  = (u16*)(ws + OFF_MID);
    float* Gx   = (float*)(ws + OFF_GX);
    u16*   tok  = (u16*)(ws + OFF_TOK);
    float* out  = (float*)d_out;

    hipMemsetAsync(d_out, 0, 33 * sizeof(float), stream);
    k_init_misc<<<128, 256, 0, stream>>>(latent, Wz, bz, Ax, Az, bar);
    k_init_gx<<<16, 256, 0, stream>>>(W_ih, b_ih, b_hh, Gx);
    k_init_tok<<<64, 256, 0, stream>>>(seq, tok);
    k_init_wfrag<<<2048, 256, 0, stream>>>(W_hh, Bf);
    k_init_wfrag2<<<2048, 256, 0, stream>>>(Wnl, Bf2);
    k_recur<<<512, 512, 0, stream>>>(tok, Gx, Bf, Ax, bar);
    k_gemm1<<<dim3(16, 128), 256, 0, stream>>>(Ax, Az, Bf2, bnl, mid);
    k_loss<<<16384, 256, 0, stream>>>(mid, Wout, bout, labels, lengths, out);
    k_final<<<1, 1, 0, stream>>>(out);
}